// Round 18
// baseline (220.034 us; speedup 1.0000x reference)
//
#include <hip/hip_runtime.h>
#include <hip/hip_bf16.h>
#include <cstdint>
#include <cstddef>

typedef unsigned short u16;
typedef short s16x8 __attribute__((ext_vector_type(8)));
typedef float f32x4 __attribute__((ext_vector_type(4)));
typedef float f32x16 __attribute__((ext_vector_type(16)));
typedef u16 u16x4 __attribute__((ext_vector_type(4)));

#define HIDDEN_C 2048
#define TSEQ 2048
#define BATCH 2
#define NHEADS 16
#define NKV 4
#define HDIM 128
#define NQKV 3072
#define BTR 4096  // BATCH*TSEQ
#define QK_SCALE 0.53033008588991f  // 6/sqrt(128)

__device__ __forceinline__ float bf2f(u16 u) {
  union { uint32_t i; float f; } v; v.i = ((uint32_t)u) << 16; return v.f;
}
__device__ __forceinline__ u16 f2bf(float f) {
  union { float f; uint32_t i; } v; v.f = f;
  uint32_t r = v.i + 0x7fffu + ((v.i >> 16) & 1u);
  return (u16)(r >> 16);
}

#define AS1(p) ((__attribute__((address_space(1))) void*)(uintptr_t)(p))
#define AS3(p) ((__attribute__((address_space(3))) void*)(p))

// ------- prep: z<4 -> W transposes; z==4 -> x fp32->bf16 + RoPE table -------
__global__ void prep_kernel(const float* __restrict__ x, u16* __restrict__ xb,
                            float2* __restrict__ tab,
                            const float* __restrict__ Wq,
                            const float* __restrict__ Wk,
                            const float* __restrict__ Wv,
                            const float* __restrict__ Wo,
                            u16* __restrict__ wqkvT,
                            u16* __restrict__ woT) {
  const int z = blockIdx.z;
  int tx = threadIdx.x, ty = threadIdx.y;
  if (z == 4) {
    int tid = ty * 32 + tx;
    int bid = blockIdx.y * 64 + blockIdx.x;
    int gi = bid * 256 + tid;
    if (gi < TSEQ * 16) {  // rope table: tab[t*16+i] = (cos,sin)(t * f_i)
      int t = gi >> 4, i = gi & 15;
      float f = powf(10000.f, -(float)i * (1.f / 16.f));
      float ang = (float)t * f;
      tab[gi] = make_float2(cosf(ang), sinf(ang));
    }
    int i = gi * 8;
    float4 a = *(const float4*)(x + i);
    float4 b = *(const float4*)(x + i + 4);
    uint4 o;
    o.x = (uint32_t)f2bf(a.x) | ((uint32_t)f2bf(a.y) << 16);
    o.y = (uint32_t)f2bf(a.z) | ((uint32_t)f2bf(a.w) << 16);
    o.z = (uint32_t)f2bf(b.x) | ((uint32_t)f2bf(b.y) << 16);
    o.w = (uint32_t)f2bf(b.z) | ((uint32_t)f2bf(b.w) << 16);
    *(uint4*)(xb + i) = o;
    return;
  }
  const float* in; u16* out; int C;
  switch (z) {
    case 0: in = Wq; out = wqkvT;                        C = 2048; break;
    case 1: in = Wk; out = wqkvT + (size_t)2048 * 2048;  C = 512;  break;
    case 2: in = Wv; out = wqkvT + (size_t)2560 * 2048;  C = 512;  break;
    default: in = Wo; out = woT;                         C = 2048; break;
  }
  int r0 = blockIdx.y * 32, c0 = blockIdx.x * 32;
  if (c0 >= C) return;
  __shared__ float tile[32][33];
  #pragma unroll
  for (int i = 0; i < 32; i += 8)
    tile[ty + i][tx] = in[(size_t)(r0 + ty + i) * C + c0 + tx];
  __syncthreads();
  #pragma unroll
  for (int i = 0; i < 32; i += 8)
    out[(size_t)(c0 + ty + i) * 2048 + r0 + tx] = f2bf(tile[tx][ty + i]);
}

// ---------------- GEMM: C[M][N] = A[M][K] * BT[N][K]^T (bf16 in, OutT out) ---
// BK=64, LDS XOR-swizzled; T1 XCD-aware block swizzle (grid %8 == 0).
// mode=1 (qkv): fused RoPE on head-local cols 0..31 + scale on Q region.
template <typename OutT>
__global__ __launch_bounds__(256) void gemm_bt_kernel(const u16* __restrict__ A,
                                                      const u16* __restrict__ BT,
                                                      OutT* __restrict__ C,
                                                      int M, int N, int K,
                                                      const float2* __restrict__ tab,
                                                      int mode) {
  __shared__ u16 As[128 * 64];
  __shared__ u16 Bs[128 * 64];
  const int tid = threadIdx.x;
  const int wave = tid >> 6, lane = tid & 63;
  const int lr = lane & 15, lg = lane >> 4;
  // T1: XCD-aware bijective remap (nwg % 8 == 0)
  const int gx = gridDim.x;
  const int bid = blockIdx.y * gx + blockIdx.x;
  const int cpx = (gx * gridDim.y) >> 3;
  const int swzb = (bid & 7) * cpx + (bid >> 3);
  const int m0 = (swzb / gx) * 128, n0 = (swzb % gx) * 128;
  const int wr = wave >> 1, wc = wave & 1;
  const int fsw = (lr & 7) << 3;  // frag-read element XOR
  f32x4 acc[4][4];
  #pragma unroll
  for (int a = 0; a < 4; ++a)
    #pragma unroll
    for (int b = 0; b < 4; ++b) acc[a][b] = (f32x4){0.f, 0.f, 0.f, 0.f};

  for (int k0 = 0; k0 < K; k0 += 64) {
    #pragma unroll
    for (int i = 0; i < 4; ++i) {
      int c = tid + i * 256;              // 1024 chunks of 16B per matrix
      int row = c >> 3, slot = c & 7;     // 8 slots per 64-elem row
      int gslot = slot ^ (row & 7);
      const u16* gA = A + (size_t)(m0 + row) * K + k0 + gslot * 8;
      const u16* gB = BT + (size_t)(n0 + row) * K + k0 + gslot * 8;
      char* lA = (char*)As + (size_t)c * 16;
      char* lB = (char*)Bs + (size_t)c * 16;
      __builtin_amdgcn_global_load_lds(AS1(gA), AS3(lA), 16, 0, 0);
      __builtin_amdgcn_global_load_lds(AS1(gB), AS3(lB), 16, 0, 0);
    }
    __syncthreads();
    #pragma unroll
    for (int kk = 0; kk < 2; ++kk) {
      s16x8 af[4], bfr[4];
      #pragma unroll
      for (int mi = 0; mi < 4; ++mi)
        af[mi] = *(const s16x8*)(As + (wr * 64 + mi * 16 + lr) * 64 + ((kk * 32 + lg * 8) ^ fsw));
      #pragma unroll
      for (int ni = 0; ni < 4; ++ni)
        bfr[ni] = *(const s16x8*)(Bs + (wc * 64 + ni * 16 + lr) * 64 + ((kk * 32 + lg * 8) ^ fsw));
      #pragma unroll
      for (int mi = 0; mi < 4; ++mi)
        #pragma unroll
        for (int ni = 0; ni < 4; ++ni)
          acc[mi][ni] = __builtin_amdgcn_mfma_f32_16x16x32_bf16(af[mi], bfr[ni], acc[mi][ni], 0, 0, 0);
    }
    __syncthreads();
  }
  // ---- fused RoPE (+ Q scale) for the qkv GEMM ----
  if (mode) {
    if (n0 < 2560 && wc == 0) {
      #pragma unroll
      for (int mi = 0; mi < 4; ++mi) {
        int rowb = m0 + wr * 64 + mi * 16 + lg * 4;
        #pragma unroll
        for (int r = 0; r < 4; ++r) {
          int t = (rowb + r) & (TSEQ - 1);
          float2 cs = tab[(t << 4) | lr];
          float a = acc[mi][0][r], b2 = acc[mi][1][r];
          acc[mi][0][r] = a * cs.x - b2 * cs.y;
          acc[mi][1][r] = b2 * cs.x + a * cs.y;
        }
      }
    }
    if (n0 < 2048) {
      #pragma unroll
      for (int mi = 0; mi < 4; ++mi)
        #pragma unroll
        for (int ni = 0; ni < 4; ++ni)
          #pragma unroll
          for (int r = 0; r < 4; ++r) acc[mi][ni][r] *= QK_SCALE;
    }
  }
  #pragma unroll
  for (int mi = 0; mi < 4; ++mi) {
    int rowb = m0 + wr * 64 + mi * 16 + lg * 4;
    #pragma unroll
    for (int ni = 0; ni < 4; ++ni) {
      int col = n0 + wc * 64 + ni * 16 + lr;
      #pragma unroll
      for (int r = 0; r < 4; ++r) {
        float v = acc[mi][ni][r];
        if constexpr (sizeof(OutT) == 2) C[(size_t)(rowb + r) * N + col] = (OutT)f2bf(v);
        else                             C[(size_t)(rowb + r) * N + col] = v;
      }
    }
  }
}

// ---------------- V [b][t][g][d] -> VT [b][g][d][t] ----------------
__global__ void transpose_v_kernel(const u16* __restrict__ qkv, u16* __restrict__ vt) {
  int bg = blockIdx.z;
  int b = bg >> 2, g = bg & 3;
  int t0 = blockIdx.x * 32, d0 = blockIdx.y * 32;
  __shared__ u16 tile[32][33];
  int tx = threadIdx.x, ty = threadIdx.y;
  #pragma unroll
  for (int i = 0; i < 32; i += 8)
    tile[ty + i][tx] = qkv[(size_t)(b * TSEQ + t0 + ty + i) * NQKV + 2560 + g * HDIM + d0 + tx];
  __syncthreads();
  #pragma unroll
  for (int i = 0; i < 32; i += 8)
    vt[((size_t)bg * HDIM + d0 + ty + i) * TSEQ + t0 + tx] = tile[tx][ty + i];
}

// ---------------- flash attention v13: KV-sharing grid decode ---------------
// idx bits: [1:0]=g, [2]=b, [3]=half, [7:4]=tile slot s, [9:8]=hq (head in
// group). Blocks differing only in hq share (b,g,tile,half) -> same K/V
// stream + same length; under round-robin they co-reside on one CU/XCD ->
// L2 reuse and matched lifetimes. hq bit1 flips tile direction so each CU's
// 4 blocks sum to 36 iters (uniform makespan). Inner loop unchanged (R15).
__global__ __launch_bounds__(256, 2) void attn_kernel(const u16* __restrict__ qkv,
                                                      const u16* __restrict__ vt,
                                                      u16* __restrict__ h0out,
                                                      u16* __restrict__ h1out,
                                                      float2* __restrict__ ml) {
  __shared__ u16 K_lds[2][64][128];   // [buf][k][d]   32 KB (16 slots/row)
  __shared__ u16 V_lds[2][128][64];   // [buf][d][k]   32 KB (8 slots/row)
  __shared__ u16 P_lds[4][32][64];    // [wave][q][k]  16 KB

  const int idx = blockIdx.x;
  const int g = idx & 3;
  const int b = (idx >> 2) & 1;
  const int half = (idx >> 3) & 1;
  const int s = (idx >> 4) & 15;
  const int hq = (idx >> 8) & 3;
  const int tile = (hq & 2) ? s : 15 - s;   // complementary backfill direction
  const int h = g * 4 + hq;
  const int tid = threadIdx.x, w = tid >> 6, lane = tid & 63;
  const int lq = lane & 31;         // q (and k/d row) index within 32
  const int hf = lane >> 5;         // lane half
  const int q0 = tile * 128;
  const int q0w = q0 + w * 32;
  const int kswz = (lq & 15) << 3;  // K read XOR (4-bit slots)
  const int vswz = (lane & 7) << 3; // V read XOR (3-bit slots)
  const int pswz = lq & 7;          // P slot swizzle key

  const u16* Qg = qkv + (size_t)b * TSEQ * NQKV + h * HDIM;
  const u16* Kg = qkv + (size_t)b * TSEQ * NQKV + HIDDEN_C + g * HDIM;
  const u16* Vg = vt + (size_t)(b * NKV + g) * HDIM * TSEQ;

  // Q frags (B-operand): col q = lq, slot d = ds*16 + hf*8 + j
  s16x8 aq[8];
  {
    const u16* qrow = Qg + (size_t)(q0w + lq) * NQKV + hf * 8;
    #pragma unroll
    for (int ds = 0; ds < 8; ++ds) aq[ds] = *(const s16x8*)(qrow + ds * 16);
  }

  // O^T accumulators: col q = lq, row d = dt*32 + (r&3) + 8*(r>>2) + 4*hf
  f32x16 O[4];
  #pragma unroll
  for (int dt = 0; dt < 4; ++dt)
    #pragma unroll
    for (int r = 0; r < 16; ++r) O[dt][r] = 0.f;
  float m_r = -1e30f, l_r = 0.f;

  auto STAGE = [&](int buf, int kb) {
    #pragma unroll
    for (int i = 0; i < 4; ++i) {          // K: 64 rows x 16 chunks of 16B
      int c = tid + i * 256;
      int row = c >> 4, slot = c & 15;
      int gslot = slot ^ (row & 15);
      const u16* src = Kg + (size_t)(kb + row) * NQKV + gslot * 8;
      char* dst = (char*)&K_lds[buf][0][0] + (size_t)c * 16;
      __builtin_amdgcn_global_load_lds(AS1(src), AS3(dst), 16, 0, 0);
    }
    #pragma unroll
    for (int i = 0; i < 4; ++i) {          // V: 128 rows(d) x 8 chunks of 16B
      int c = tid + i * 256;
      int row = c >> 3, slot = c & 7;
      int gslot = slot ^ (row & 7);
      const u16* src = Vg + (size_t)row * TSEQ + kb + gslot * 8;
      char* dst = (char*)&V_lds[buf][0][0] + (size_t)c * 16;
      __builtin_amdgcn_global_load_lds(AS1(src), AS3(dst), 16, 0, 0);
    }
  };

  const int t0i = half * (tile + 1);   // first k-tile (KVBLK=64)
  const int t1i = t0i + (tile + 1);    // one past last
  STAGE(0, t0i * 64);
  asm volatile("s_waitcnt vmcnt(0)" ::: "memory");
  __syncthreads();

  for (int tt = t0i; tt < t1i; ++tt) {
    const int kb = tt * 64;
    const int cur = (tt - t0i) & 1;
    if (tt + 1 < t1i) STAGE(cur ^ 1, kb + 64);

    if (kb <= q0w + 31) {
      // ---- QK^T (swapped, 32x32x16): S^T[k][q] per k-half ----
      f32x16 S[2];
      #pragma unroll
      for (int kh = 0; kh < 2; ++kh)
        #pragma unroll
        for (int r = 0; r < 16; ++r) S[kh][r] = 0.f;
      __builtin_amdgcn_s_setprio(1);
      #pragma unroll
      for (int kh = 0; kh < 2; ++kh) {
        const u16* krow = &K_lds[cur][kh * 32 + lq][0];
        #pragma unroll
        for (int ds = 0; ds < 8; ++ds) {
          s16x8 ak = *(const s16x8*)(krow + ((ds * 16 + hf * 8) ^ kswz));
          S[kh] = __builtin_amdgcn_mfma_f32_32x32x16_bf16(ak, aq[ds], S[kh], 0, 0, 0);
        }
      }
      __builtin_amdgcn_s_setprio(0);
      // ---- causal mask: k > q -> -1e30 (C/D map: row=(r&3)+8*(r>>2)+4*hf) ----
      if (kb + 63 > q0w) {
        const int q = q0w + lq;
        #pragma unroll
        for (int kh = 0; kh < 2; ++kh)
          #pragma unroll
          for (int r = 0; r < 16; ++r) {
            int k = kb + kh * 32 + (r & 3) + 8 * (r >> 2) + 4 * hf;
            if (k > q) S[kh][r] = -1e30f;
          }
      }
      // ---- online softmax (in-register trees + cross-half shfl) ----
      f32x16 pm;
      #pragma unroll
      for (int r = 0; r < 16; ++r) pm[r] = fmaxf(S[0][r], S[1][r]);
      float m8[8];
      #pragma unroll
      for (int r = 0; r < 8; ++r) m8[r] = fmaxf(pm[r], pm[r + 8]);
      float mx = fmaxf(fmaxf(fmaxf(m8[0], m8[4]), fmaxf(m8[1], m8[5])),
                       fmaxf(fmaxf(m8[2], m8[6]), fmaxf(m8[3], m8[7])));
      mx = fmaxf(mx, __shfl_xor(mx, 32));
      // defer-max (T13): rescale only when the tile max grew beyond THR=8
      if (!__all(mx <= m_r + 8.f)) {
        const float mn = fmaxf(m_r, mx);
        const float al = __expf(m_r - mn);
        m_r = mn;
        l_r *= al;
        #pragma unroll
        for (int dt = 0; dt < 4; ++dt)
          #pragma unroll
          for (int r = 0; r < 16; ++r) O[dt][r] *= al;
      }
      #pragma unroll
      for (int kh = 0; kh < 2; ++kh)
        #pragma unroll
        for (int r = 0; r < 16; ++r) S[kh][r] = __expf(S[kh][r] - m_r);
      f32x16 sv;
      #pragma unroll
      for (int r = 0; r < 16; ++r) sv[r] = S[0][r] + S[1][r];
      float s8[8];
      #pragma unroll
      for (int r = 0; r < 8; ++r) s8[r] = sv[r] + sv[r + 8];
      float ps = ((s8[0] + s8[4]) + (s8[1] + s8[5])) + ((s8[2] + s8[6]) + (s8[3] + s8[7]));
      ps += __shfl_xor(ps, 32);
      l_r += ps;
      // ---- P -> LDS (swizzled u16x4 path) ----
      u16* pw = &P_lds[w][lq][0];
      #pragma unroll
      for (int kh = 0; kh < 2; ++kh)
        #pragma unroll
        for (int r2 = 0; r2 < 4; ++r2) {
          u16x4 hq4;
          #pragma unroll
          for (int j = 0; j < 4; ++j) hq4[j] = f2bf(S[kh][r2 * 4 + j]);
          int slot = kh * 4 + r2;
          *(u16x4*)(pw + ((slot ^ pswz) << 3) + hf * 4) = hq4;
        }
      asm volatile("s_waitcnt lgkmcnt(0)" ::: "memory");
      __builtin_amdgcn_sched_barrier(0);
      // ---- PV (swapped, 32x32x16): O^T += mfma(V^T, P^T) ----
      s16x8 pb[4];
      #pragma unroll
      for (int ks = 0; ks < 4; ++ks) {
        int slot = ks * 2 + hf;
        pb[ks] = *(const s16x8*)(pw + ((slot ^ pswz) << 3));
      }
      __builtin_amdgcn_s_setprio(1);
      #pragma unroll
      for (int dt = 0; dt < 4; ++dt) {
        const u16* vrow = &V_lds[cur][dt * 32 + lq][0];
        #pragma unroll
        for (int ks = 0; ks < 4; ++ks) {
          s16x8 av = *(const s16x8*)(vrow + ((ks * 16 + hf * 8) ^ vswz));
          O[dt] = __builtin_amdgcn_mfma_f32_32x32x16_bf16(av, pb[ks], O[dt], 0, 0, 0);
        }
      }
      __builtin_amdgcn_s_setprio(0);
    }
    asm volatile("s_waitcnt vmcnt(0)" ::: "memory");
    __syncthreads();
  }

  // epilogue: UNNORMALIZED O-half -> h0out/h1out; (m,l) -> ml
  u16* obase = (half ? h1out : h0out);
  u16* orow = obase + (size_t)(b * TSEQ + q0w + lq) * HIDDEN_C + h * HDIM + hf * 4;
  #pragma unroll
  for (int dt = 0; dt < 4; ++dt)
    #pragma unroll
    for (int r2 = 0; r2 < 4; ++r2) {
      u16x4 o4;
      #pragma unroll
      for (int j = 0; j < 4; ++j) o4[j] = f2bf(O[dt][r2 * 4 + j]);
      *(u16x4*)(orow + dt * 32 + r2 * 8) = o4;
    }
  if (hf == 0)
    ml[(((size_t)half * BATCH + b) * NHEADS + h) * TSEQ + q0w + lq] = make_float2(m_r, l_r);
}

// ------- combine: out = (o0*e0 + o1*e1) / (l0*e0 + l1*e1), e_i = e^{m_i-m} ---
__global__ void combine_kernel(const u16* __restrict__ h0, u16* __restrict__ h1out,
                               const float2* __restrict__ ml) {
  int gi = blockIdx.x * blockDim.x + threadIdx.x;
  size_t base = (size_t)gi * 8;
  int bt = (int)(base >> 11);       // b*TSEQ + q
  int c = (int)(base & 2047);
  int h = c >> 7;
  int b = bt >> 11, q = bt & (TSEQ - 1);
  float2 v0 = ml[((size_t)(0 * BATCH + b) * NHEADS + h) * TSEQ + q];
  float2 v1 = ml[((size_t)(1 * BATCH + b) * NHEADS + h) * TSEQ + q];
  float m = fmaxf(v0.x, v1.x);
  float e0 = __expf(v0.x - m);
  float e1 = __expf(v1.x - m);
  float inv = 1.f / (v0.y * e0 + v1.y * e1);
  float w0 = e0 * inv, w1 = e1 * inv;
  uint4 a = *(const uint4*)(h0 + base);
  uint4 d = *(const uint4*)(h1out + base);
  const uint32_t* au = (const uint32_t*)&a;
  const uint32_t* du = (const uint32_t*)&d;
  uint4 o;
  uint32_t* ou = (uint32_t*)&o;
  #pragma unroll
  for (int j = 0; j < 4; ++j) {
    float lo = bf2f((u16)(au[j] & 0xffff)) * w0 + bf2f((u16)(du[j] & 0xffff)) * w1;
    float hi = bf2f((u16)(au[j] >> 16)) * w0 + bf2f((u16)(du[j] >> 16)) * w1;
    ou[j] = (uint32_t)f2bf(lo) | ((uint32_t)f2bf(hi) << 16);
  }
  *(uint4*)(h1out + base) = o;
}

extern "C" void kernel_launch(void* const* d_in, const int* in_sizes, int n_in,
                              void* d_out, int out_size, void* d_ws, size_t ws_size,
                              hipStream_t stream) {
  const float* x  = (const float*)d_in[0];
  const float* Wq = (const float*)d_in[1];
  const float* Wk = (const float*)d_in[2];
  const float* Wv = (const float*)d_in[3];
  const float* Wo = (const float*)d_in[4];
  float* out = (float*)d_out;
  char* ws = (char*)d_ws;

  u16* xb    = (u16*)(ws);                          // 16 MiB (x bf16; reused as attn half0)
  u16* wqkvT = (u16*)(ws + (size_t)(16u << 20));    // 12 MiB  [3072][2048]
  u16* woT   = (u16*)(ws + (size_t)(28u << 20));    //  8 MiB  [2048][2048]
  u16* qkv   = (u16*)(ws + (size_t)(36u << 20));    // 24 MiB  [4096][3072]
  u16* vtb   = (u16*)(ws + (size_t)(60u << 20));    //  4 MiB  [2][4][128][2048]
  u16* attn  = (u16*)(ws + (size_t)(64u << 20));    // 16 MiB  [4096][2048] (half1 + combined)
  float2* rope_tab = (float2*)(ws + (size_t)(64u << 20));  // 256 KiB (dead before attn writes)
  float2* mlbuf = (float2*)(ws + (size_t)(80u << 20));     //   2 MiB [half][b][h][q]

  dim3 tb(32, 8);
  prep_kernel<<<dim3(64, 64, 5), tb, 0, stream>>>(x, xb, rope_tab, Wq, Wk, Wv, Wo, wqkvT, woT);

  gemm_bt_kernel<u16><<<dim3(NQKV / 128, BTR / 128), 256, 0, stream>>>(
      xb, wqkvT, qkv, BTR, NQKV, HIDDEN_C, rope_tab, 1);

  transpose_v_kernel<<<dim3(TSEQ / 32, HDIM / 32, BATCH * NKV), tb, 0, stream>>>(qkv, vtb);

  attn_kernel<<<1024, 256, 0, stream>>>(qkv, vtb, xb, attn, mlbuf);

  combine_kernel<<<(BTR * HIDDEN_C / 8) / 256, 256, 0, stream>>>(xb, attn, mlbuf);

  gemm_bt_kernel<float><<<dim3(HIDDEN_C / 128, BTR / 128), 256, 0, stream>>>(
      attn, woT, out, BTR, HIDDEN_C, HIDDEN_C, nullptr, 0);
}

// Round 19
// 204.356 us; speedup vs baseline: 1.0767x; 1.0767x over previous
//
#include <hip/hip_runtime.h>
#include <hip/hip_bf16.h>
#include <cstdint>
#include <cstddef>

typedef unsigned short u16;
typedef short s16x8 __attribute__((ext_vector_type(8)));
typedef float f32x4 __attribute__((ext_vector_type(4)));
typedef float f32x16 __attribute__((ext_vector_type(16)));
typedef u16 u16x4 __attribute__((ext_vector_type(4)));

#define HIDDEN_C 2048
#define TSEQ 2048
#define BATCH 2
#define NHEADS 16
#define NKV 4
#define HDIM 128
#define NQKV 3072
#define BTR 4096  // BATCH*TSEQ
#define QK_SCALE 0.53033008588991f  // 6/sqrt(128)

__device__ __forceinline__ float bf2f(u16 u) {
  union { uint32_t i; float f; } v; v.i = ((uint32_t)u) << 16; return v.f;
}
__device__ __forceinline__ u16 f2bf(float f) {
  union { float f; uint32_t i; } v; v.f = f;
  uint32_t r = v.i + 0x7fffu + ((v.i >> 16) & 1u);
  return (u16)(r >> 16);
}

#define AS1(p) ((__attribute__((address_space(1))) void*)(uintptr_t)(p))
#define AS3(p) ((__attribute__((address_space(3))) void*)(p))

// ------- prep: z<4 -> W transposes; z==4 -> x fp32->bf16 + RoPE table -------
__global__ void prep_kernel(const float* __restrict__ x, u16* __restrict__ xb,
                            float2* __restrict__ tab,
                            const float* __restrict__ Wq,
                            const float* __restrict__ Wk,
                            const float* __restrict__ Wv,
                            const float* __restrict__ Wo,
                            u16* __restrict__ wqkvT,
                            u16* __restrict__ woT) {
  const int z = blockIdx.z;
  int tx = threadIdx.x, ty = threadIdx.y;
  if (z == 4) {
    int tid = ty * 32 + tx;
    int bid = blockIdx.y * 64 + blockIdx.x;
    int gi = bid * 256 + tid;
    if (gi < TSEQ * 16) {  // rope table: tab[t*16+i] = (cos,sin)(t * f_i)
      int t = gi >> 4, i = gi & 15;
      float f = powf(10000.f, -(float)i * (1.f / 16.f));
      float ang = (float)t * f;
      tab[gi] = make_float2(cosf(ang), sinf(ang));
    }
    int i = gi * 8;
    float4 a = *(const float4*)(x + i);
    float4 b = *(const float4*)(x + i + 4);
    uint4 o;
    o.x = (uint32_t)f2bf(a.x) | ((uint32_t)f2bf(a.y) << 16);
    o.y = (uint32_t)f2bf(a.z) | ((uint32_t)f2bf(a.w) << 16);
    o.z = (uint32_t)f2bf(b.x) | ((uint32_t)f2bf(b.y) << 16);
    o.w = (uint32_t)f2bf(b.z) | ((uint32_t)f2bf(b.w) << 16);
    *(uint4*)(xb + i) = o;
    return;
  }
  const float* in; u16* out; int C;
  switch (z) {
    case 0: in = Wq; out = wqkvT;                        C = 2048; break;
    case 1: in = Wk; out = wqkvT + (size_t)2048 * 2048;  C = 512;  break;
    case 2: in = Wv; out = wqkvT + (size_t)2560 * 2048;  C = 512;  break;
    default: in = Wo; out = woT;                         C = 2048; break;
  }
  int r0 = blockIdx.y * 32, c0 = blockIdx.x * 32;
  if (c0 >= C) return;
  __shared__ float tile[32][33];
  #pragma unroll
  for (int i = 0; i < 32; i += 8)
    tile[ty + i][tx] = in[(size_t)(r0 + ty + i) * C + c0 + tx];
  __syncthreads();
  #pragma unroll
  for (int i = 0; i < 32; i += 8)
    out[(size_t)(c0 + ty + i) * 2048 + r0 + tx] = f2bf(tile[tx][ty + i]);
}

// ---------------- GEMM: C[M][N] = A[M][K] * BT[N][K]^T (bf16 in, OutT out) ---
// BK=64, LDS XOR-swizzled; T1 XCD-aware block swizzle (grid %8 == 0).
// mode=1 (qkv): fused RoPE on head-local cols 0..31 + scale on Q region.
template <typename OutT>
__global__ __launch_bounds__(256) void gemm_bt_kernel(const u16* __restrict__ A,
                                                      const u16* __restrict__ BT,
                                                      OutT* __restrict__ C,
                                                      int M, int N, int K,
                                                      const float2* __restrict__ tab,
                                                      int mode) {
  __shared__ u16 As[128 * 64];
  __shared__ u16 Bs[128 * 64];
  const int tid = threadIdx.x;
  const int wave = tid >> 6, lane = tid & 63;
  const int lr = lane & 15, lg = lane >> 4;
  // T1: XCD-aware bijective remap (nwg % 8 == 0)
  const int gx = gridDim.x;
  const int bid = blockIdx.y * gx + blockIdx.x;
  const int cpx = (gx * gridDim.y) >> 3;
  const int swzb = (bid & 7) * cpx + (bid >> 3);
  const int m0 = (swzb / gx) * 128, n0 = (swzb % gx) * 128;
  const int wr = wave >> 1, wc = wave & 1;
  const int fsw = (lr & 7) << 3;  // frag-read element XOR
  f32x4 acc[4][4];
  #pragma unroll
  for (int a = 0; a < 4; ++a)
    #pragma unroll
    for (int b = 0; b < 4; ++b) acc[a][b] = (f32x4){0.f, 0.f, 0.f, 0.f};

  for (int k0 = 0; k0 < K; k0 += 64) {
    #pragma unroll
    for (int i = 0; i < 4; ++i) {
      int c = tid + i * 256;              // 1024 chunks of 16B per matrix
      int row = c >> 3, slot = c & 7;     // 8 slots per 64-elem row
      int gslot = slot ^ (row & 7);
      const u16* gA = A + (size_t)(m0 + row) * K + k0 + gslot * 8;
      const u16* gB = BT + (size_t)(n0 + row) * K + k0 + gslot * 8;
      char* lA = (char*)As + (size_t)c * 16;
      char* lB = (char*)Bs + (size_t)c * 16;
      __builtin_amdgcn_global_load_lds(AS1(gA), AS3(lA), 16, 0, 0);
      __builtin_amdgcn_global_load_lds(AS1(gB), AS3(lB), 16, 0, 0);
    }
    __syncthreads();
    #pragma unroll
    for (int kk = 0; kk < 2; ++kk) {
      s16x8 af[4], bfr[4];
      #pragma unroll
      for (int mi = 0; mi < 4; ++mi)
        af[mi] = *(const s16x8*)(As + (wr * 64 + mi * 16 + lr) * 64 + ((kk * 32 + lg * 8) ^ fsw));
      #pragma unroll
      for (int ni = 0; ni < 4; ++ni)
        bfr[ni] = *(const s16x8*)(Bs + (wc * 64 + ni * 16 + lr) * 64 + ((kk * 32 + lg * 8) ^ fsw));
      #pragma unroll
      for (int mi = 0; mi < 4; ++mi)
        #pragma unroll
        for (int ni = 0; ni < 4; ++ni)
          acc[mi][ni] = __builtin_amdgcn_mfma_f32_16x16x32_bf16(af[mi], bfr[ni], acc[mi][ni], 0, 0, 0);
    }
    __syncthreads();
  }
  // ---- fused RoPE (+ Q scale) for the qkv GEMM ----
  if (mode) {
    if (n0 < 2560 && wc == 0) {
      #pragma unroll
      for (int mi = 0; mi < 4; ++mi) {
        int rowb = m0 + wr * 64 + mi * 16 + lg * 4;
        #pragma unroll
        for (int r = 0; r < 4; ++r) {
          int t = (rowb + r) & (TSEQ - 1);
          float2 cs = tab[(t << 4) | lr];
          float a = acc[mi][0][r], b2 = acc[mi][1][r];
          acc[mi][0][r] = a * cs.x - b2 * cs.y;
          acc[mi][1][r] = b2 * cs.x + a * cs.y;
        }
      }
    }
    if (n0 < 2048) {
      #pragma unroll
      for (int mi = 0; mi < 4; ++mi)
        #pragma unroll
        for (int ni = 0; ni < 4; ++ni)
          #pragma unroll
          for (int r = 0; r < 4; ++r) acc[mi][ni][r] *= QK_SCALE;
    }
  }
  #pragma unroll
  for (int mi = 0; mi < 4; ++mi) {
    int rowb = m0 + wr * 64 + mi * 16 + lg * 4;
    #pragma unroll
    for (int ni = 0; ni < 4; ++ni) {
      int col = n0 + wc * 64 + ni * 16 + lr;
      #pragma unroll
      for (int r = 0; r < 4; ++r) {
        float v = acc[mi][ni][r];
        if constexpr (sizeof(OutT) == 2) C[(size_t)(rowb + r) * N + col] = (OutT)f2bf(v);
        else                             C[(size_t)(rowb + r) * N + col] = v;
      }
    }
  }
}

// ---------------- V [b][t][g][d] -> VT [b][g][d][t] ----------------
__global__ void transpose_v_kernel(const u16* __restrict__ qkv, u16* __restrict__ vt) {
  int bg = blockIdx.z;
  int b = bg >> 2, g = bg & 3;
  int t0 = blockIdx.x * 32, d0 = blockIdx.y * 32;
  __shared__ u16 tile[32][33];
  int tx = threadIdx.x, ty = threadIdx.y;
  #pragma unroll
  for (int i = 0; i < 32; i += 8)
    tile[ty + i][tx] = qkv[(size_t)(b * TSEQ + t0 + ty + i) * NQKV + 2560 + g * HDIM + d0 + tx];
  __syncthreads();
  #pragma unroll
  for (int i = 0; i < 32; i += 8)
    vt[((size_t)bg * HDIM + d0 + ty + i) * TSEQ + t0 + tx] = tile[tx][ty + i];
}

// ---------------- flash attention (R17 config): k-split, KVBLK=64 -----------
// 1024 blocks: (tile desc, half, bh). half0: k in [0,64(t+1)); half1: rest.
// Both halves are (t+1) iters -> uniform block lengths; 80 KB LDS, 2 blk/CU.
// Mixed-length co-residency desynchronizes stalls (R18 lesson: lockstep
// same-KV pairing is net negative despite 4x FETCH reduction).
__global__ __launch_bounds__(256, 2) void attn_kernel(const u16* __restrict__ qkv,
                                                      const u16* __restrict__ vt,
                                                      u16* __restrict__ h0out,
                                                      u16* __restrict__ h1out,
                                                      float2* __restrict__ ml) {
  __shared__ u16 K_lds[2][64][128];   // [buf][k][d]   32 KB (16 slots/row)
  __shared__ u16 V_lds[2][128][64];   // [buf][d][k]   32 KB (8 slots/row)
  __shared__ u16 P_lds[4][32][64];    // [wave][q][k]  16 KB

  const int idx = blockIdx.x;
  const int tile = 15 - (idx >> 6);             // longest first
  const int half = idx & 1;
  const int bh = (idx >> 1) & 31;
  const int h = bh & 15, b = bh >> 4, g = h >> 2;
  const int tid = threadIdx.x, w = tid >> 6, lane = tid & 63;
  const int lq = lane & 31;         // q (and k/d row) index within 32
  const int hf = lane >> 5;         // lane half
  const int q0 = tile * 128;
  const int q0w = q0 + w * 32;
  const int kswz = (lq & 15) << 3;  // K read XOR (4-bit slots)
  const int vswz = (lane & 7) << 3; // V read XOR (3-bit slots)
  const int pswz = lq & 7;          // P slot swizzle key

  const u16* Qg = qkv + (size_t)b * TSEQ * NQKV + h * HDIM;
  const u16* Kg = qkv + (size_t)b * TSEQ * NQKV + HIDDEN_C + g * HDIM;
  const u16* Vg = vt + (size_t)(b * NKV + g) * HDIM * TSEQ;

  // Q frags (B-operand): col q = lq, slot d = ds*16 + hf*8 + j
  s16x8 aq[8];
  {
    const u16* qrow = Qg + (size_t)(q0w + lq) * NQKV + hf * 8;
    #pragma unroll
    for (int ds = 0; ds < 8; ++ds) aq[ds] = *(const s16x8*)(qrow + ds * 16);
  }

  // O^T accumulators: col q = lq, row d = dt*32 + (r&3) + 8*(r>>2) + 4*hf
  f32x16 O[4];
  #pragma unroll
  for (int dt = 0; dt < 4; ++dt)
    #pragma unroll
    for (int r = 0; r < 16; ++r) O[dt][r] = 0.f;
  float m_r = -1e30f, l_r = 0.f;

  auto STAGE = [&](int buf, int kb) {
    #pragma unroll
    for (int i = 0; i < 4; ++i) {          // K: 64 rows x 16 chunks of 16B
      int c = tid + i * 256;
      int row = c >> 4, slot = c & 15;
      int gslot = slot ^ (row & 15);
      const u16* src = Kg + (size_t)(kb + row) * NQKV + gslot * 8;
      char* dst = (char*)&K_lds[buf][0][0] + (size_t)c * 16;
      __builtin_amdgcn_global_load_lds(AS1(src), AS3(dst), 16, 0, 0);
    }
    #pragma unroll
    for (int i = 0; i < 4; ++i) {          // V: 128 rows(d) x 8 chunks of 16B
      int c = tid + i * 256;
      int row = c >> 3, slot = c & 7;
      int gslot = slot ^ (row & 7);
      const u16* src = Vg + (size_t)row * TSEQ + kb + gslot * 8;
      char* dst = (char*)&V_lds[buf][0][0] + (size_t)c * 16;
      __builtin_amdgcn_global_load_lds(AS1(src), AS3(dst), 16, 0, 0);
    }
  };

  const int t0i = half * (tile + 1);   // first k-tile (KVBLK=64)
  const int t1i = t0i + (tile + 1);    // one past last
  STAGE(0, t0i * 64);
  asm volatile("s_waitcnt vmcnt(0)" ::: "memory");
  __syncthreads();

  for (int tt = t0i; tt < t1i; ++tt) {
    const int kb = tt * 64;
    const int cur = (tt - t0i) & 1;
    if (tt + 1 < t1i) STAGE(cur ^ 1, kb + 64);

    if (kb <= q0w + 31) {
      // ---- QK^T (swapped, 32x32x16): S^T[k][q] per k-half ----
      f32x16 S[2];
      #pragma unroll
      for (int kh = 0; kh < 2; ++kh)
        #pragma unroll
        for (int r = 0; r < 16; ++r) S[kh][r] = 0.f;
      __builtin_amdgcn_s_setprio(1);
      #pragma unroll
      for (int kh = 0; kh < 2; ++kh) {
        const u16* krow = &K_lds[cur][kh * 32 + lq][0];
        #pragma unroll
        for (int ds = 0; ds < 8; ++ds) {
          s16x8 ak = *(const s16x8*)(krow + ((ds * 16 + hf * 8) ^ kswz));
          S[kh] = __builtin_amdgcn_mfma_f32_32x32x16_bf16(ak, aq[ds], S[kh], 0, 0, 0);
        }
      }
      __builtin_amdgcn_s_setprio(0);
      // ---- causal mask: k > q -> -1e30 (C/D map: row=(r&3)+8*(r>>2)+4*hf) ----
      if (kb + 63 > q0w) {
        const int q = q0w + lq;
        #pragma unroll
        for (int kh = 0; kh < 2; ++kh)
          #pragma unroll
          for (int r = 0; r < 16; ++r) {
            int k = kb + kh * 32 + (r & 3) + 8 * (r >> 2) + 4 * hf;
            if (k > q) S[kh][r] = -1e30f;
          }
      }
      // ---- online softmax (in-register trees + cross-half shfl) ----
      f32x16 pm;
      #pragma unroll
      for (int r = 0; r < 16; ++r) pm[r] = fmaxf(S[0][r], S[1][r]);
      float m8[8];
      #pragma unroll
      for (int r = 0; r < 8; ++r) m8[r] = fmaxf(pm[r], pm[r + 8]);
      float mx = fmaxf(fmaxf(fmaxf(m8[0], m8[4]), fmaxf(m8[1], m8[5])),
                       fmaxf(fmaxf(m8[2], m8[6]), fmaxf(m8[3], m8[7])));
      mx = fmaxf(mx, __shfl_xor(mx, 32));
      // defer-max (T13): rescale only when the tile max grew beyond THR=8
      if (!__all(mx <= m_r + 8.f)) {
        const float mn = fmaxf(m_r, mx);
        const float al = __expf(m_r - mn);
        m_r = mn;
        l_r *= al;
        #pragma unroll
        for (int dt = 0; dt < 4; ++dt)
          #pragma unroll
          for (int r = 0; r < 16; ++r) O[dt][r] *= al;
      }
      #pragma unroll
      for (int kh = 0; kh < 2; ++kh)
        #pragma unroll
        for (int r = 0; r < 16; ++r) S[kh][r] = __expf(S[kh][r] - m_r);
      f32x16 sv;
      #pragma unroll
      for (int r = 0; r < 16; ++r) sv[r] = S[0][r] + S[1][r];
      float s8[8];
      #pragma unroll
      for (int r = 0; r < 8; ++r) s8[r] = sv[r] + sv[r + 8];
      float ps = ((s8[0] + s8[4]) + (s8[1] + s8[5])) + ((s8[2] + s8[6]) + (s8[3] + s8[7]));
      ps += __shfl_xor(ps, 32);
      l_r += ps;
      // ---- P -> LDS (swizzled u16x4 path) ----
      u16* pw = &P_lds[w][lq][0];
      #pragma unroll
      for (int kh = 0; kh < 2; ++kh)
        #pragma unroll
        for (int r2 = 0; r2 < 4; ++r2) {
          u16x4 hq;
          #pragma unroll
          for (int j = 0; j < 4; ++j) hq[j] = f2bf(S[kh][r2 * 4 + j]);
          int slot = kh * 4 + r2;
          *(u16x4*)(pw + ((slot ^ pswz) << 3) + hf * 4) = hq;
        }
      asm volatile("s_waitcnt lgkmcnt(0)" ::: "memory");
      __builtin_amdgcn_sched_barrier(0);
      // ---- PV (swapped, 32x32x16): O^T += mfma(V^T, P^T) ----
      s16x8 pb[4];
      #pragma unroll
      for (int ks = 0; ks < 4; ++ks) {
        int slot = ks * 2 + hf;
        pb[ks] = *(const s16x8*)(pw + ((slot ^ pswz) << 3));
      }
      __builtin_amdgcn_s_setprio(1);
      #pragma unroll
      for (int dt = 0; dt < 4; ++dt) {
        const u16* vrow = &V_lds[cur][dt * 32 + lq][0];
        #pragma unroll
        for (int ks = 0; ks < 4; ++ks) {
          s16x8 av = *(const s16x8*)(vrow + ((ks * 16 + hf * 8) ^ vswz));
          O[dt] = __builtin_amdgcn_mfma_f32_32x32x16_bf16(av, pb[ks], O[dt], 0, 0, 0);
        }
      }
      __builtin_amdgcn_s_setprio(0);
    }
    asm volatile("s_waitcnt vmcnt(0)" ::: "memory");
    __syncthreads();
  }

  // epilogue: UNNORMALIZED O-half -> h0out/h1out; (m,l) -> ml
  u16* obase = (half ? h1out : h0out);
  u16* orow = obase + (size_t)(b * TSEQ + q0w + lq) * HIDDEN_C + h * HDIM + hf * 4;
  #pragma unroll
  for (int dt = 0; dt < 4; ++dt)
    #pragma unroll
    for (int r2 = 0; r2 < 4; ++r2) {
      u16x4 o4;
      #pragma unroll
      for (int j = 0; j < 4; ++j) o4[j] = f2bf(O[dt][r2 * 4 + j]);
      *(u16x4*)(orow + dt * 32 + r2 * 8) = o4;
    }
  if (hf == 0)
    ml[(((size_t)half * BATCH + b) * NHEADS + h) * TSEQ + q0w + lq] = make_float2(m_r, l_r);
}

// ------- combine: out = (o0*e0 + o1*e1) / (l0*e0 + l1*e1), e_i = e^{m_i-m} ---
__global__ void combine_kernel(const u16* __restrict__ h0, u16* __restrict__ h1out,
                               const float2* __restrict__ ml) {
  int gi = blockIdx.x * blockDim.x + threadIdx.x;
  size_t base = (size_t)gi * 8;
  int bt = (int)(base >> 11);       // b*TSEQ + q
  int c = (int)(base & 2047);
  int h = c >> 7;
  int b = bt >> 11, q = bt & (TSEQ - 1);
  float2 v0 = ml[((size_t)(0 * BATCH + b) * NHEADS + h) * TSEQ + q];
  float2 v1 = ml[((size_t)(1 * BATCH + b) * NHEADS + h) * TSEQ + q];
  float m = fmaxf(v0.x, v1.x);
  float e0 = __expf(v0.x - m);
  float e1 = __expf(v1.x - m);
  float inv = 1.f / (v0.y * e0 + v1.y * e1);
  float w0 = e0 * inv, w1 = e1 * inv;
  uint4 a = *(const uint4*)(h0 + base);
  uint4 d = *(const uint4*)(h1out + base);
  const uint32_t* au = (const uint32_t*)&a;
  const uint32_t* du = (const uint32_t*)&d;
  uint4 o;
  uint32_t* ou = (uint32_t*)&o;
  #pragma unroll
  for (int j = 0; j < 4; ++j) {
    float lo = bf2f((u16)(au[j] & 0xffff)) * w0 + bf2f((u16)(du[j] & 0xffff)) * w1;
    float hi = bf2f((u16)(au[j] >> 16)) * w0 + bf2f((u16)(du[j] >> 16)) * w1;
    ou[j] = (uint32_t)f2bf(lo) | ((uint32_t)f2bf(hi) << 16);
  }
  *(uint4*)(h1out + base) = o;
}

extern "C" void kernel_launch(void* const* d_in, const int* in_sizes, int n_in,
                              void* d_out, int out_size, void* d_ws, size_t ws_size,
                              hipStream_t stream) {
  const float* x  = (const float*)d_in[0];
  const float* Wq = (const float*)d_in[1];
  const float* Wk = (const float*)d_in[2];
  const float* Wv = (const float*)d_in[3];
  const float* Wo = (const float*)d_in[4];
  float* out = (float*)d_out;
  char* ws = (char*)d_ws;

  u16* xb    = (u16*)(ws);                          // 16 MiB (x bf16; reused as attn half0)
  u16* wqkvT = (u16*)(ws + (size_t)(16u << 20));    // 12 MiB  [3072][2048]
  u16* woT   = (u16*)(ws + (size_t)(28u << 20));    //  8 MiB  [2048][2048]
  u16* qkv   = (u16*)(ws + (size_t)(36u << 20));    // 24 MiB  [4096][3072]
  u16* vtb   = (u16*)(ws + (size_t)(60u << 20));    //  4 MiB  [2][4][128][2048]
  u16* attn  = (u16*)(ws + (size_t)(64u << 20));    // 16 MiB  [4096][2048] (half1 + combined)
  float2* rope_tab = (float2*)(ws + (size_t)(64u << 20));  // 256 KiB (dead before attn writes)
  float2* mlbuf = (float2*)(ws + (size_t)(80u << 20));     //   2 MiB [half][b][h][q]

  dim3 tb(32, 8);
  prep_kernel<<<dim3(64, 64, 5), tb, 0, stream>>>(x, xb, rope_tab, Wq, Wk, Wv, Wo, wqkvT, woT);

  gemm_bt_kernel<u16><<<dim3(NQKV / 128, BTR / 128), 256, 0, stream>>>(
      xb, wqkvT, qkv, BTR, NQKV, HIDDEN_C, rope_tab, 1);

  transpose_v_kernel<<<dim3(TSEQ / 32, HDIM / 32, BATCH * NKV), tb, 0, stream>>>(qkv, vtb);

  attn_kernel<<<1024, 256, 0, stream>>>(qkv, vtb, xb, attn, mlbuf);

  combine_kernel<<<(BTR * HIDDEN_C / 8) / 256, 256, 0, stream>>>(xb, attn, mlbuf);

  gemm_bt_kernel<float><<<dim3(HIDDEN_C / 128, BTR / 128), 256, 0, stream>>>(
      attn, woT, out, BTR, HIDDEN_C, HIDDEN_C, nullptr, 0);
}

// Round 20
// 203.863 us; speedup vs baseline: 1.0793x; 1.0024x over previous
//
#include <hip/hip_runtime.h>
#include <hip/hip_bf16.h>
#include <cstdint>
#include <cstddef>

typedef unsigned short u16;
typedef short s16x8 __attribute__((ext_vector_type(8)));
typedef float f32x4 __attribute__((ext_vector_type(4)));
typedef float f32x16 __attribute__((ext_vector_type(16)));
typedef u16 u16x4 __attribute__((ext_vector_type(4)));

#define HIDDEN_C 2048
#define TSEQ 2048
#define BATCH 2
#define NHEADS 16
#define NKV 4
#define HDIM 128
#define NQKV 3072
#define BTR 4096  // BATCH*TSEQ
#define QK_SCALE 0.53033008588991f  // 6/sqrt(128)

__device__ __forceinline__ float bf2f(u16 u) {
  union { uint32_t i; float f; } v; v.i = ((uint32_t)u) << 16; return v.f;
}
__device__ __forceinline__ u16 f2bf(float f) {
  union { float f; uint32_t i; } v; v.f = f;
  uint32_t r = v.i + 0x7fffu + ((v.i >> 16) & 1u);
  return (u16)(r >> 16);
}

#define AS1(p) ((__attribute__((address_space(1))) void*)(uintptr_t)(p))
#define AS3(p) ((__attribute__((address_space(3))) void*)(p))

// ------- prep: z<4 -> W transposes; z==4 -> x fp32->bf16 + RoPE table -------
__global__ void prep_kernel(const float* __restrict__ x, u16* __restrict__ xb,
                            float2* __restrict__ tab,
                            const float* __restrict__ Wq,
                            const float* __restrict__ Wk,
                            const float* __restrict__ Wv,
                            const float* __restrict__ Wo,
                            u16* __restrict__ wqkvT,
                            u16* __restrict__ woT) {
  const int z = blockIdx.z;
  int tx = threadIdx.x, ty = threadIdx.y;
  if (z == 4) {
    int tid = ty * 32 + tx;
    int bid = blockIdx.y * 64 + blockIdx.x;
    int gi = bid * 256 + tid;
    if (gi < TSEQ * 16) {  // rope table: tab[t*16+i] = (cos,sin)(t * f_i)
      int t = gi >> 4, i = gi & 15;
      float f = powf(10000.f, -(float)i * (1.f / 16.f));
      float ang = (float)t * f;
      tab[gi] = make_float2(cosf(ang), sinf(ang));
    }
    int i = gi * 8;
    float4 a = *(const float4*)(x + i);
    float4 b = *(const float4*)(x + i + 4);
    uint4 o;
    o.x = (uint32_t)f2bf(a.x) | ((uint32_t)f2bf(a.y) << 16);
    o.y = (uint32_t)f2bf(a.z) | ((uint32_t)f2bf(a.w) << 16);
    o.z = (uint32_t)f2bf(b.x) | ((uint32_t)f2bf(b.y) << 16);
    o.w = (uint32_t)f2bf(b.z) | ((uint32_t)f2bf(b.w) << 16);
    *(uint4*)(xb + i) = o;
    return;
  }
  const float* in; u16* out; int C;
  switch (z) {
    case 0: in = Wq; out = wqkvT;                        C = 2048; break;
    case 1: in = Wk; out = wqkvT + (size_t)2048 * 2048;  C = 512;  break;
    case 2: in = Wv; out = wqkvT + (size_t)2560 * 2048;  C = 512;  break;
    default: in = Wo; out = woT;                         C = 2048; break;
  }
  int r0 = blockIdx.y * 32, c0 = blockIdx.x * 32;
  if (c0 >= C) return;
  __shared__ float tile[32][33];
  #pragma unroll
  for (int i = 0; i < 32; i += 8)
    tile[ty + i][tx] = in[(size_t)(r0 + ty + i) * C + c0 + tx];
  __syncthreads();
  #pragma unroll
  for (int i = 0; i < 32; i += 8)
    out[(size_t)(c0 + ty + i) * 2048 + r0 + tx] = f2bf(tile[tx][ty + i]);
}

// ---------------- GEMM: C[M][N] = A[M][K] * BT[N][K]^T (bf16 in, OutT out) ---
// BK=64, LDS XOR-swizzled; T1 XCD-aware block swizzle (grid %8 == 0).
// mode=1 (qkv): fused RoPE on head-local cols 0..31 + scale on Q region.
template <typename OutT>
__global__ __launch_bounds__(256) void gemm_bt_kernel(const u16* __restrict__ A,
                                                      const u16* __restrict__ BT,
                                                      OutT* __restrict__ C,
                                                      int M, int N, int K,
                                                      const float2* __restrict__ tab,
                                                      int mode) {
  __shared__ u16 As[128 * 64];
  __shared__ u16 Bs[128 * 64];
  const int tid = threadIdx.x;
  const int wave = tid >> 6, lane = tid & 63;
  const int lr = lane & 15, lg = lane >> 4;
  // T1: XCD-aware bijective remap (nwg % 8 == 0)
  const int gx = gridDim.x;
  const int bid = blockIdx.y * gx + blockIdx.x;
  const int cpx = (gx * gridDim.y) >> 3;
  const int swzb = (bid & 7) * cpx + (bid >> 3);
  const int m0 = (swzb / gx) * 128, n0 = (swzb % gx) * 128;
  const int wr = wave >> 1, wc = wave & 1;
  const int fsw = (lr & 7) << 3;  // frag-read element XOR
  f32x4 acc[4][4];
  #pragma unroll
  for (int a = 0; a < 4; ++a)
    #pragma unroll
    for (int b = 0; b < 4; ++b) acc[a][b] = (f32x4){0.f, 0.f, 0.f, 0.f};

  for (int k0 = 0; k0 < K; k0 += 64) {
    #pragma unroll
    for (int i = 0; i < 4; ++i) {
      int c = tid + i * 256;              // 1024 chunks of 16B per matrix
      int row = c >> 3, slot = c & 7;     // 8 slots per 64-elem row
      int gslot = slot ^ (row & 7);
      const u16* gA = A + (size_t)(m0 + row) * K + k0 + gslot * 8;
      const u16* gB = BT + (size_t)(n0 + row) * K + k0 + gslot * 8;
      char* lA = (char*)As + (size_t)c * 16;
      char* lB = (char*)Bs + (size_t)c * 16;
      __builtin_amdgcn_global_load_lds(AS1(gA), AS3(lA), 16, 0, 0);
      __builtin_amdgcn_global_load_lds(AS1(gB), AS3(lB), 16, 0, 0);
    }
    __syncthreads();
    #pragma unroll
    for (int kk = 0; kk < 2; ++kk) {
      s16x8 af[4], bfr[4];
      #pragma unroll
      for (int mi = 0; mi < 4; ++mi)
        af[mi] = *(const s16x8*)(As + (wr * 64 + mi * 16 + lr) * 64 + ((kk * 32 + lg * 8) ^ fsw));
      #pragma unroll
      for (int ni = 0; ni < 4; ++ni)
        bfr[ni] = *(const s16x8*)(Bs + (wc * 64 + ni * 16 + lr) * 64 + ((kk * 32 + lg * 8) ^ fsw));
      #pragma unroll
      for (int mi = 0; mi < 4; ++mi)
        #pragma unroll
        for (int ni = 0; ni < 4; ++ni)
          acc[mi][ni] = __builtin_amdgcn_mfma_f32_16x16x32_bf16(af[mi], bfr[ni], acc[mi][ni], 0, 0, 0);
    }
    __syncthreads();
  }
  // ---- fused RoPE (+ Q scale) for the qkv GEMM ----
  if (mode) {
    if (n0 < 2560 && wc == 0) {
      #pragma unroll
      for (int mi = 0; mi < 4; ++mi) {
        int rowb = m0 + wr * 64 + mi * 16 + lg * 4;
        #pragma unroll
        for (int r = 0; r < 4; ++r) {
          int t = (rowb + r) & (TSEQ - 1);
          float2 cs = tab[(t << 4) | lr];
          float a = acc[mi][0][r], b2 = acc[mi][1][r];
          acc[mi][0][r] = a * cs.x - b2 * cs.y;
          acc[mi][1][r] = b2 * cs.x + a * cs.y;
        }
      }
    }
    if (n0 < 2048) {
      #pragma unroll
      for (int mi = 0; mi < 4; ++mi)
        #pragma unroll
        for (int ni = 0; ni < 4; ++ni)
          #pragma unroll
          for (int r = 0; r < 4; ++r) acc[mi][ni][r] *= QK_SCALE;
    }
  }
  #pragma unroll
  for (int mi = 0; mi < 4; ++mi) {
    int rowb = m0 + wr * 64 + mi * 16 + lg * 4;
    #pragma unroll
    for (int ni = 0; ni < 4; ++ni) {
      int col = n0 + wc * 64 + ni * 16 + lr;
      #pragma unroll
      for (int r = 0; r < 4; ++r) {
        float v = acc[mi][ni][r];
        if constexpr (sizeof(OutT) == 2) C[(size_t)(rowb + r) * N + col] = (OutT)f2bf(v);
        else                             C[(size_t)(rowb + r) * N + col] = v;
      }
    }
  }
}

// ---------------- V [b][t][g][d] -> VT [b][g][d][t], vectorized -------------
// 64x64 tile, 256 threads; u16x4 (8B/lane) on both global read and write.
__global__ __launch_bounds__(256) void transpose_v_kernel(const u16* __restrict__ qkv,
                                                          u16* __restrict__ vt) {
  int bg = blockIdx.z;
  int b = bg >> 2, g = bg & 3;
  int t0 = blockIdx.x * 64, d0 = blockIdx.y * 64;
  __shared__ u16 tile[64][68];   // [d][t], pad 68 to break b64 bank patterns
  const int tid = threadIdx.y * 32 + threadIdx.x;
  const int c16 = tid & 15, r16 = tid >> 4;   // 16 lanes x 16 rows
  // read: rows t = t0 + r16 + pass*16, cols d = d0 + c16*4 (u16x4)
  #pragma unroll
  for (int pass = 0; pass < 4; ++pass) {
    int t = r16 + pass * 16;
    u16x4 v = *(const u16x4*)(qkv + (size_t)(b * TSEQ + t0 + t) * NQKV + 2560 + g * HDIM + d0 + c16 * 4);
    #pragma unroll
    for (int j = 0; j < 4; ++j) tile[c16 * 4 + j][t] = v[j];
  }
  __syncthreads();
  // write: rows d = d0 + r16 + pass*16, cols t = t0 + c16*4 (u16x4)
  #pragma unroll
  for (int pass = 0; pass < 4; ++pass) {
    int d = r16 + pass * 16;
    u16x4 v = *(const u16x4*)(&tile[d][c16 * 4]);
    *(u16x4*)(vt + ((size_t)bg * HDIM + d0 + d) * TSEQ + t0 + c16 * 4) = v;
  }
}

// ---------------- flash attention (R17 config): k-split, KVBLK=64 -----------
// 1024 blocks: (tile desc, half, bh). half0: k in [0,64(t+1)); half1: rest.
// Both halves are (t+1) iters -> uniform block lengths; 80 KB LDS, 2 blk/CU.
// Mixed-length co-residency desynchronizes stalls (R18 lesson: lockstep
// same-KV pairing is net negative despite 4x FETCH reduction).
__global__ __launch_bounds__(256, 2) void attn_kernel(const u16* __restrict__ qkv,
                                                      const u16* __restrict__ vt,
                                                      u16* __restrict__ h0out,
                                                      u16* __restrict__ h1out,
                                                      float2* __restrict__ ml) {
  __shared__ u16 K_lds[2][64][128];   // [buf][k][d]   32 KB (16 slots/row)
  __shared__ u16 V_lds[2][128][64];   // [buf][d][k]   32 KB (8 slots/row)
  __shared__ u16 P_lds[4][32][64];    // [wave][q][k]  16 KB

  const int idx = blockIdx.x;
  const int tile = 15 - (idx >> 6);             // longest first
  const int half = idx & 1;
  const int bh = (idx >> 1) & 31;
  const int h = bh & 15, b = bh >> 4, g = h >> 2;
  const int tid = threadIdx.x, w = tid >> 6, lane = tid & 63;
  const int lq = lane & 31;         // q (and k/d row) index within 32
  const int hf = lane >> 5;         // lane half
  const int q0 = tile * 128;
  const int q0w = q0 + w * 32;
  const int kswz = (lq & 15) << 3;  // K read XOR (4-bit slots)
  const int vswz = (lane & 7) << 3; // V read XOR (3-bit slots)
  const int pswz = lq & 7;          // P slot swizzle key

  const u16* Qg = qkv + (size_t)b * TSEQ * NQKV + h * HDIM;
  const u16* Kg = qkv + (size_t)b * TSEQ * NQKV + HIDDEN_C + g * HDIM;
  const u16* Vg = vt + (size_t)(b * NKV + g) * HDIM * TSEQ;

  // Q frags (B-operand): col q = lq, slot d = ds*16 + hf*8 + j
  s16x8 aq[8];
  {
    const u16* qrow = Qg + (size_t)(q0w + lq) * NQKV + hf * 8;
    #pragma unroll
    for (int ds = 0; ds < 8; ++ds) aq[ds] = *(const s16x8*)(qrow + ds * 16);
  }

  // O^T accumulators: col q = lq, row d = dt*32 + (r&3) + 8*(r>>2) + 4*hf
  f32x16 O[4];
  #pragma unroll
  for (int dt = 0; dt < 4; ++dt)
    #pragma unroll
    for (int r = 0; r < 16; ++r) O[dt][r] = 0.f;
  float m_r = -1e30f, l_r = 0.f;

  auto STAGE = [&](int buf, int kb) {
    #pragma unroll
    for (int i = 0; i < 4; ++i) {          // K: 64 rows x 16 chunks of 16B
      int c = tid + i * 256;
      int row = c >> 4, slot = c & 15;
      int gslot = slot ^ (row & 15);
      const u16* src = Kg + (size_t)(kb + row) * NQKV + gslot * 8;
      char* dst = (char*)&K_lds[buf][0][0] + (size_t)c * 16;
      __builtin_amdgcn_global_load_lds(AS1(src), AS3(dst), 16, 0, 0);
    }
    #pragma unroll
    for (int i = 0; i < 4; ++i) {          // V: 128 rows(d) x 8 chunks of 16B
      int c = tid + i * 256;
      int row = c >> 3, slot = c & 7;
      int gslot = slot ^ (row & 7);
      const u16* src = Vg + (size_t)row * TSEQ + kb + gslot * 8;
      char* dst = (char*)&V_lds[buf][0][0] + (size_t)c * 16;
      __builtin_amdgcn_global_load_lds(AS1(src), AS3(dst), 16, 0, 0);
    }
  };

  const int t0i = half * (tile + 1);   // first k-tile (KVBLK=64)
  const int t1i = t0i + (tile + 1);    // one past last
  STAGE(0, t0i * 64);
  asm volatile("s_waitcnt vmcnt(0)" ::: "memory");
  __syncthreads();

  for (int tt = t0i; tt < t1i; ++tt) {
    const int kb = tt * 64;
    const int cur = (tt - t0i) & 1;
    if (tt + 1 < t1i) STAGE(cur ^ 1, kb + 64);

    if (kb <= q0w + 31) {
      // ---- QK^T (swapped, 32x32x16): S^T[k][q] per k-half ----
      f32x16 S[2];
      #pragma unroll
      for (int kh = 0; kh < 2; ++kh)
        #pragma unroll
        for (int r = 0; r < 16; ++r) S[kh][r] = 0.f;
      __builtin_amdgcn_s_setprio(1);
      #pragma unroll
      for (int kh = 0; kh < 2; ++kh) {
        const u16* krow = &K_lds[cur][kh * 32 + lq][0];
        #pragma unroll
        for (int ds = 0; ds < 8; ++ds) {
          s16x8 ak = *(const s16x8*)(krow + ((ds * 16 + hf * 8) ^ kswz));
          S[kh] = __builtin_amdgcn_mfma_f32_32x32x16_bf16(ak, aq[ds], S[kh], 0, 0, 0);
        }
      }
      __builtin_amdgcn_s_setprio(0);
      // ---- causal mask: k > q -> -1e30 (C/D map: row=(r&3)+8*(r>>2)+4*hf) ----
      if (kb + 63 > q0w) {
        const int q = q0w + lq;
        #pragma unroll
        for (int kh = 0; kh < 2; ++kh)
          #pragma unroll
          for (int r = 0; r < 16; ++r) {
            int k = kb + kh * 32 + (r & 3) + 8 * (r >> 2) + 4 * hf;
            if (k > q) S[kh][r] = -1e30f;
          }
      }
      // ---- online softmax (in-register trees + cross-half shfl) ----
      f32x16 pm;
      #pragma unroll
      for (int r = 0; r < 16; ++r) pm[r] = fmaxf(S[0][r], S[1][r]);
      float m8[8];
      #pragma unroll
      for (int r = 0; r < 8; ++r) m8[r] = fmaxf(pm[r], pm[r + 8]);
      float mx = fmaxf(fmaxf(fmaxf(m8[0], m8[4]), fmaxf(m8[1], m8[5])),
                       fmaxf(fmaxf(m8[2], m8[6]), fmaxf(m8[3], m8[7])));
      mx = fmaxf(mx, __shfl_xor(mx, 32));
      // defer-max (T13): rescale only when the tile max grew beyond THR=8
      if (!__all(mx <= m_r + 8.f)) {
        const float mn = fmaxf(m_r, mx);
        const float al = __expf(m_r - mn);
        m_r = mn;
        l_r *= al;
        #pragma unroll
        for (int dt = 0; dt < 4; ++dt)
          #pragma unroll
          for (int r = 0; r < 16; ++r) O[dt][r] *= al;
      }
      #pragma unroll
      for (int kh = 0; kh < 2; ++kh)
        #pragma unroll
        for (int r = 0; r < 16; ++r) S[kh][r] = __expf(S[kh][r] - m_r);
      f32x16 sv;
      #pragma unroll
      for (int r = 0; r < 16; ++r) sv[r] = S[0][r] + S[1][r];
      float s8[8];
      #pragma unroll
      for (int r = 0; r < 8; ++r) s8[r] = sv[r] + sv[r + 8];
      float ps = ((s8[0] + s8[4]) + (s8[1] + s8[5])) + ((s8[2] + s8[6]) + (s8[3] + s8[7]));
      ps += __shfl_xor(ps, 32);
      l_r += ps;
      // ---- P -> LDS (swizzled u16x4 path) ----
      u16* pw = &P_lds[w][lq][0];
      #pragma unroll
      for (int kh = 0; kh < 2; ++kh)
        #pragma unroll
        for (int r2 = 0; r2 < 4; ++r2) {
          u16x4 hq;
          #pragma unroll
          for (int j = 0; j < 4; ++j) hq[j] = f2bf(S[kh][r2 * 4 + j]);
          int slot = kh * 4 + r2;
          *(u16x4*)(pw + ((slot ^ pswz) << 3) + hf * 4) = hq;
        }
      asm volatile("s_waitcnt lgkmcnt(0)" ::: "memory");
      __builtin_amdgcn_sched_barrier(0);
      // ---- PV (swapped, 32x32x16): O^T += mfma(V^T, P^T) ----
      s16x8 pb[4];
      #pragma unroll
      for (int ks = 0; ks < 4; ++ks) {
        int slot = ks * 2 + hf;
        pb[ks] = *(const s16x8*)(pw + ((slot ^ pswz) << 3));
      }
      __builtin_amdgcn_s_setprio(1);
      #pragma unroll
      for (int dt = 0; dt < 4; ++dt) {
        const u16* vrow = &V_lds[cur][dt * 32 + lq][0];
        #pragma unroll
        for (int ks = 0; ks < 4; ++ks) {
          s16x8 av = *(const s16x8*)(vrow + ((ks * 16 + hf * 8) ^ vswz));
          O[dt] = __builtin_amdgcn_mfma_f32_32x32x16_bf16(av, pb[ks], O[dt], 0, 0, 0);
        }
      }
      __builtin_amdgcn_s_setprio(0);
    }
    asm volatile("s_waitcnt vmcnt(0)" ::: "memory");
    __syncthreads();
  }

  // epilogue: UNNORMALIZED O-half -> h0out/h1out; (m,l) -> ml
  u16* obase = (half ? h1out : h0out);
  u16* orow = obase + (size_t)(b * TSEQ + q0w + lq) * HIDDEN_C + h * HDIM + hf * 4;
  #pragma unroll
  for (int dt = 0; dt < 4; ++dt)
    #pragma unroll
    for (int r2 = 0; r2 < 4; ++r2) {
      u16x4 o4;
      #pragma unroll
      for (int j = 0; j < 4; ++j) o4[j] = f2bf(O[dt][r2 * 4 + j]);
      *(u16x4*)(orow + dt * 32 + r2 * 8) = o4;
    }
  if (hf == 0)
    ml[(((size_t)half * BATCH + b) * NHEADS + h) * TSEQ + q0w + lq] = make_float2(m_r, l_r);
}

// ------- combine: out = (o0*e0 + o1*e1) / (l0*e0 + l1*e1), e_i = e^{m_i-m} ---
__global__ void combine_kernel(const u16* __restrict__ h0, u16* __restrict__ h1out,
                               const float2* __restrict__ ml) {
  int gi = blockIdx.x * blockDim.x + threadIdx.x;
  size_t base = (size_t)gi * 8;
  int bt = (int)(base >> 11);       // b*TSEQ + q
  int c = (int)(base & 2047);
  int h = c >> 7;
  int b = bt >> 11, q = bt & (TSEQ - 1);
  float2 v0 = ml[((size_t)(0 * BATCH + b) * NHEADS + h) * TSEQ + q];
  float2 v1 = ml[((size_t)(1 * BATCH + b) * NHEADS + h) * TSEQ + q];
  float m = fmaxf(v0.x, v1.x);
  float e0 = __expf(v0.x - m);
  float e1 = __expf(v1.x - m);
  float inv = 1.f / (v0.y * e0 + v1.y * e1);
  float w0 = e0 * inv, w1 = e1 * inv;
  uint4 a = *(const uint4*)(h0 + base);
  uint4 d = *(const uint4*)(h1out + base);
  const uint32_t* au = (const uint32_t*)&a;
  const uint32_t* du = (const uint32_t*)&d;
  uint4 o;
  uint32_t* ou = (uint32_t*)&o;
  #pragma unroll
  for (int j = 0; j < 4; ++j) {
    float lo = bf2f((u16)(au[j] & 0xffff)) * w0 + bf2f((u16)(du[j] & 0xffff)) * w1;
    float hi = bf2f((u16)(au[j] >> 16)) * w0 + bf2f((u16)(du[j] >> 16)) * w1;
    ou[j] = (uint32_t)f2bf(lo) | ((uint32_t)f2bf(hi) << 16);
  }
  *(uint4*)(h1out + base) = o;
}

extern "C" void kernel_launch(void* const* d_in, const int* in_sizes, int n_in,
                              void* d_out, int out_size, void* d_ws, size_t ws_size,
                              hipStream_t stream) {
  const float* x  = (const float*)d_in[0];
  const float* Wq = (const float*)d_in[1];
  const float* Wk = (const float*)d_in[2];
  const float* Wv = (const float*)d_in[3];
  const float* Wo = (const float*)d_in[4];
  float* out = (float*)d_out;
  char* ws = (char*)d_ws;

  u16* xb    = (u16*)(ws);                          // 16 MiB (x bf16; reused as attn half0)
  u16* wqkvT = (u16*)(ws + (size_t)(16u << 20));    // 12 MiB  [3072][2048]
  u16* woT   = (u16*)(ws + (size_t)(28u << 20));    //  8 MiB  [2048][2048]
  u16* qkv   = (u16*)(ws + (size_t)(36u << 20));    // 24 MiB  [4096][3072]
  u16* vtb   = (u16*)(ws + (size_t)(60u << 20));    //  4 MiB  [2][4][128][2048]
  u16* attn  = (u16*)(ws + (size_t)(64u << 20));    // 16 MiB  [4096][2048] (half1 + combined)
  float2* rope_tab = (float2*)(ws + (size_t)(64u << 20));  // 256 KiB (dead before attn writes)
  float2* mlbuf = (float2*)(ws + (size_t)(80u << 20));     //   2 MiB [half][b][h][q]

  dim3 tb(32, 8);
  prep_kernel<<<dim3(64, 64, 5), tb, 0, stream>>>(x, xb, rope_tab, Wq, Wk, Wv, Wo, wqkvT, woT);

  gemm_bt_kernel<u16><<<dim3(NQKV / 128, BTR / 128), 256, 0, stream>>>(
      xb, wqkvT, qkv, BTR, NQKV, HIDDEN_C, rope_tab, 1);

  transpose_v_kernel<<<dim3(TSEQ / 64, HDIM / 64, BATCH * NKV), tb, 0, stream>>>(qkv, vtb);

  attn_kernel<<<1024, 256, 0, stream>>>(qkv, vtb, xb, attn, mlbuf);

  combine_kernel<<<(BTR * HIDDEN_C / 8) / 256, 256, 0, stream>>>(xb, attn, mlbuf);

  gemm_bt_kernel<float><<<dim3(HIDDEN_C / 128, BTR / 128), 256, 0, stream>>>(
      attn, woT, out, BTR, HIDDEN_C, HIDDEN_C, nullptr, 0);
}